// Round 8
// baseline (3650.094 us; speedup 1.0000x reference)
//
#include <hip/hip_runtime.h>
#include <hip/hip_fp16.h>

// ---------------------------------------------------------------------------
// 2-layer LSTM (T=512, B=128, H=512) + linear head, persistent-kernel design.
// Round 8: RMW-free, group-barrier-free sync fabric.
//  - Release: ONE relaxed store to a per-producer flag word (own 128B line).
//  - Acquire: lane-parallel reads of the 16/32 producer flag lines (reads
//    pipeline in the LLC; only RMWs serialize -- R3/R6 evidence).
//  - No end-of-step group barrier: consumers gate at the top of their own
//    step; producers skip their own flag. Back-pressure amortized (L1 polls
//    L2 flags every 8 steps; h2 depth-2 ring gated via kh1 poll + block
//    barrier transitivity).
//  - Data-visibility: R5's proven store -> sync -> verify8 -> sync -> flag.
//  - Compute path = R7: register-resident B-slices (64 rows/wave), batched
//    A-fragment loads, linear head off the critical path.
// ---------------------------------------------------------------------------

#define HDIM   512
#define TSTEPS 512
#define BATCH  128
#define DIN    5
#define NGRP   4
#define MGRP   32
#define NB1    16
#define NB2    32
#define RING   16

#define OFF_W1 0u            // packed layer1 weights: 16 blocks * 128KB = 2MB
#define OFF_W2 2097152u      // packed layer2 weights: 32 blocks * 128KB = 4MB
#define OFF_H1 6291456u      // h1 ring: 4 * 16 * 32 * 512 fp16 = 2MB
#define OFF_H2 8388608u      // h2 ring: 4 * 2 * 32 * 512 fp16 = 256KB
#define OFF_F1 8650752u      // flags1: 4 grp * 16 producers * 128B line = 8KB
#define OFF_F2 8658944u      // flags2: 4 grp * 32 producers * 128B line = 16KB
#define WS_END 8675328u

typedef _Float16 half8 __attribute__((ext_vector_type(8)));
typedef float    floatx4 __attribute__((ext_vector_type(4)));

__device__ __forceinline__ float sigf(float v) { return 1.0f / (1.0f + __expf(-v)); }

// 16B A-fragment read: two cache-bypassing relaxed 8B atomic loads (to LLC).
__device__ __forceinline__ half8 ring_ld16(const _Float16* p) {
  union { unsigned long long u[2]; half8 h; } r;
  unsigned long long* q = (unsigned long long*)p;
  r.u[0] = __hip_atomic_load(q,     __ATOMIC_RELAXED, __HIP_MEMORY_SCOPE_AGENT);
  r.u[1] = __hip_atomic_load(q + 1, __ATOMIC_RELAXED, __HIP_MEMORY_SCOPE_AGENT);
  return r.h;
}
__device__ __forceinline__ void ring_st8(_Float16* p, unsigned long long v) {
  __hip_atomic_store((unsigned long long*)p, v, __ATOMIC_RELAXED, __HIP_MEMORY_SCOPE_AGENT);
}
// Spin until the 8B at p reads back as v (data proven readable at the LLC
// coherency point; later flag readers then must see it).
__device__ __forceinline__ void verify8(const _Float16* p, unsigned long long v) {
  while (__hip_atomic_load((unsigned long long*)p, __ATOMIC_RELAXED,
                           __HIP_MEMORY_SCOPE_AGENT) != v)
    ;
}
__device__ __forceinline__ void flag_st(unsigned* p, unsigned v) {
  __hip_atomic_store(p, v, __ATOMIC_RELAXED, __HIP_MEMORY_SCOPE_AGENT);
}
// Lane-parallel poll of n producer flags, each on its own 128B line
// (stride 32 u32). Reads pipeline across LLC banks; no RMW anywhere.
__device__ __forceinline__ void pollNs(const unsigned* f, int n, unsigned tgt,
                                       int lane, int skip) {
  for (;;) {
    unsigned v = tgt;
    if (lane < n && lane != skip)
      v = __hip_atomic_load(f + (size_t)lane * 32, __ATOMIC_RELAXED,
                            __HIP_MEMORY_SCOPE_AGENT);
    if (__all((int)(v >= tgt))) break;
  }
  __asm__ __volatile__("" ::: "memory");
}

// ---------------------------------------------------------------------------
extern "C" __global__ void init_kernel(char* __restrict__ ws, float* __restrict__ out,
                                       const float* __restrict__ blin) {
  unsigned tid = blockIdx.x * 256u + threadIdx.x;
  unsigned nz = (WS_END - OFF_H1) / 16u;
  if (tid < nz) ((uint4*)(ws + OFF_H1))[tid] = make_uint4(0, 0, 0, 0);
  if (tid < (unsigned)(BATCH * TSTEPS)) out[tid] = blin[0];
}

// Pack fp32 weights -> fp16 MFMA B-fragment layout (unchanged since round 2).
extern "C" __global__ void pack_kernel(const float* __restrict__ Whh1,
                                       const float* __restrict__ Wih2,
                                       const float* __restrict__ Whh2,
                                       char* __restrict__ ws) {
  unsigned tid = blockIdx.x * 256u + threadIdx.x;
  const float* src;
  char* dst;
  if (tid < 131072u) {
    unsigned lane = tid & 63u, ks = (tid >> 6) & 15u, gg = (tid >> 10) & 3u,
             h = (tid >> 12) & 1u, j = tid >> 13;
    unsigned cg = j * 32u + h * 16u + (lane & 15u);
    unsigned row = gg * 512u + cg;
    unsigned k0 = ks * 32u + (lane >> 4) * 8u;
    src = Whh1 + (size_t)row * 512u + k0;
    dst = ws + OFF_W1 + (size_t)tid * 16u;
  } else {
    unsigned t2 = tid - 131072u;
    if (t2 >= 262144u) return;
    unsigned lane = t2 & 63u, ksl = (t2 >> 6) & 15u, gg = (t2 >> 10) & 3u,
             kh = (t2 >> 12) & 1u, j = t2 >> 13;
    unsigned cg = j * 16u + (lane & 15u);
    unsigned row = gg * 512u + cg;
    unsigned kp = kh * 512u + ksl * 32u + (lane >> 4) * 8u;
    src = (kp < 512u) ? (Wih2 + (size_t)row * 512u + kp)
                      : (Whh2 + (size_t)row * 512u + (kp - 512u));
    dst = ws + OFF_W2 + (size_t)t2 * 16u;
  }
  float4 lo = ((const float4*)src)[0];
  float4 hi = ((const float4*)src)[1];
  _Float16 v[8] = {(_Float16)lo.x, (_Float16)lo.y, (_Float16)lo.z, (_Float16)lo.w,
                   (_Float16)hi.x, (_Float16)hi.y, (_Float16)hi.z, (_Float16)hi.w};
  *(uint4*)dst = *(const uint4*)v;
}

// ---------------------------------------------------------------------------
extern "C" __global__ __launch_bounds__(256, 1) void lstm_persist(
    const float* __restrict__ x,
    const float* __restrict__ Wih1,
    const float* __restrict__ bih1, const float* __restrict__ bhh1,
    const float* __restrict__ bih2, const float* __restrict__ bhh2,
    const float* __restrict__ Wlin,
    float* __restrict__ out,
    char* __restrict__ ws) {
  __shared__ char smem[16384];

  const int blk = blockIdx.x;
  const int xcd = blk & 7;
  const int slot = blk >> 3;
  const int tid = threadIdx.x;
  const int wave = tid >> 6;
  const int lane = tid & 63;
  const int nlane = lane & 15;
  const int quad = lane >> 4;

  _Float16* h1ring = (_Float16*)(ws + OFF_H1);
  _Float16* h2ring = (_Float16*)(ws + OFF_H2);
  unsigned* fl1 = (unsigned*)(ws + OFF_F1);  // [g][producer j] stride 32 u32
  unsigned* fl2 = (unsigned*)(ws + OFF_F2);  // [g][producer j] stride 32 u32

  if (xcd >= NGRP) {
    // ------------------------------ layer 1 -------------------------------
    const int g = xcd - NGRP;
    const int j = slot;
    if (j >= NB1) return;
    const char* gW = ws + OFF_W1 + (size_t)j * 131072u;

    const int mt = wave >> 1;  // batch half (16 rows)
    const int hh = wave & 1;   // column half (16 cols)
    const int cg = j * 32 + hh * 16 + nlane;
    const unsigned* f1 = fl1 + (size_t)g * NB1 * 32;
    const unsigned* f2 = fl2 + (size_t)g * NB2 * 32;
    unsigned* myflag = fl1 + ((size_t)g * NB1 + j) * 32;
    _Float16* ring = h1ring + (size_t)g * (RING * MGRP * HDIM);
    _Float16* tile = (_Float16*)smem;  // 32x32 fp16 = 2KB

    // persistent B-slice: 64 rows x 16B/lane = 256 VGPRs, loaded once
    half8 breg[64];
#pragma unroll
    for (int r = 0; r < 64; ++r)
      breg[r] = *(const half8*)(gW + (size_t)((hh * 64 + r) * 64 + lane) * 16);

    float bias_r[4], wih[4][5];
    for (int gg = 0; gg < 4; ++gg) {
      int row = gg * 512 + cg;
      bias_r[gg] = bih1[row] + bhh1[row];
      for (int k = 0; k < 5; ++k) wih[gg][k] = Wih1[row * 5 + k];
    }
    float cstate[4] = {};

    for (int t = 0; t < TSTEPS; ++t) {
      // acquire: peers' h1(t-1) flags (own j skipped -- written+verified by us)
      if (t) pollNs(f1, NB1, (unsigned)t, lane, j);
      // amortized ring back-pressure (slot t%16 holds h1(t-16); L2 flag >= t-8
      // means it consumed h1 up to t-9; lead t..t+7 overwrites t-16..t-9) ok
      if (wave == 0 && (t & 7) == 0 && t >= 16)
        pollNs(f2, NB2, (unsigned)(t - 8), lane, -1);

      // batched A-fragment loads (32 independent 8B LLC loads -> pipeline)
      const _Float16* aprev =
          ring + (size_t)((t + RING - 1) % RING) * (MGRP * HDIM) +
          mt * 16 * HDIM + nlane * HDIM + quad * 8;
      half8 a[16];
#pragma unroll
      for (int ks = 0; ks < 16; ++ks) a[ks] = ring_ld16(aprev + ks * 32);

      // acc init = bias + x_t @ W_ih1^T (fp32, K=5) -- overlaps A-load latency
      float xr[4][5];
#pragma unroll
      for (int r = 0; r < 4; ++r) {
        int b = g * MGRP + mt * 16 + quad * 4 + r;
        const float* xp = x + ((size_t)t * BATCH + b) * DIN;
#pragma unroll
        for (int k = 0; k < 5; ++k) xr[r][k] = xp[k];
      }
      floatx4 acc[4];
#pragma unroll
      for (int gg = 0; gg < 4; ++gg) {
#pragma unroll
        for (int r = 0; r < 4; ++r) {
          float s = bias_r[gg];
#pragma unroll
          for (int k = 0; k < 5; ++k) s += xr[r][k] * wih[gg][k];
          acc[gg][r] = s;
        }
      }
      // 64 register-fed MFMAs: no memory ops in this loop
#pragma unroll
      for (int ks = 0; ks < 16; ++ks) {
#pragma unroll
        for (int gg = 0; gg < 4; ++gg)
          acc[gg] = __builtin_amdgcn_mfma_f32_16x16x32_f16(a[ks], breg[gg * 16 + ks],
                                                           acc[gg], 0, 0, 0);
      }
      // gates -> LDS transpose tile (32 rows x 32 cols fp16)
#pragma unroll
      for (int r = 0; r < 4; ++r) {
        float iv = acc[0][r], fv = acc[1][r], gv = acc[2][r], ov = acc[3][r];
        float cn = sigf(fv) * cstate[r] + sigf(iv) * tanhf(gv);
        float hn = sigf(ov) * tanhf(cn);
        cstate[r] = cn;
        tile[(mt * 16 + quad * 4 + r) * 32 + hh * 16 + nlane] = (_Float16)hn;
      }
      __syncthreads();
      // ring store: 256 threads x 8B, coalesced, LLC write-through
      _Float16* hout = ring + (size_t)(t % RING) * (MGRP * HDIM);
      unsigned long long v =
          *(const unsigned long long*)(tile + (tid >> 3) * 32 + (tid & 7) * 4);
      _Float16* dst = hout + (tid >> 3) * HDIM + j * 32 + (tid & 7) * 4;
      ring_st8(dst, v);
      __syncthreads();   // all stores issued & ack'd
      verify8(dst, v);   // proven readable at LLC coherency point
      __syncthreads();   // all threads verified
      if (tid == 0) flag_st(myflag, (unsigned)(t + 1));  // release: ONE store
    }
  } else {
    // ------------------------------ layer 2 -------------------------------
    const int g = xcd;
    const int j = slot;
    const char* gW = ws + OFF_W2 + (size_t)j * 131072u;

    const int kh = wave & 1;   // 0 -> h1(t) (W_ih2 half), 1 -> h2(t-1) (W_hh2 half)
    const int mt = wave >> 1;  // batch half
    const int cg = j * 16 + nlane;
    const unsigned* f1 = fl1 + (size_t)g * NB1 * 32;
    const unsigned* f2 = fl2 + (size_t)g * NB2 * 32;
    unsigned* myflag = fl2 + ((size_t)g * NB2 + j) * 32;
    const _Float16* h1rd = h1ring + (size_t)g * (RING * MGRP * HDIM);
    _Float16* ring2 = h2ring + (size_t)g * (2 * MGRP * HDIM);
    floatx4* pbase = (floatx4*)smem;                 // 8KB
    _Float16* tile2 = (_Float16*)(smem + 8192);      // 32x16 fp16 = 1KB

    // persistent B-slice: 64 rows x 16B/lane = 256 VGPRs, loaded once
    half8 breg[64];
#pragma unroll
    for (int r = 0; r < 64; ++r)
      breg[r] = *(const half8*)(gW + (size_t)((kh * 64 + r) * 64 + lane) * 16);

    float bias_r[4];
    for (int gg = 0; gg < 4; ++gg) {
      int row = gg * 512 + cg;
      bias_r[gg] = bih2[row] + bhh2[row];
    }
    const float wl = Wlin[cg];
    float cstate[4] = {};

    for (int t = 0; t < TSTEPS; ++t) {
      // acquire: kh0 needs h1(t) (f1 >= t+1); kh1 needs peers' h2(t-1)
      // (f2 >= t; peers having finished t-1 also implies slot t&1 consumed,
      // and the block barrier below extends that guarantee to the writers).
      if (kh == 0) pollNs(f1, NB1, (unsigned)(t + 1), lane, -1);
      else if (t) pollNs(f2, NB2, (unsigned)t, lane, j);

      const _Float16* abase = (kh == 0)
          ? h1rd + (size_t)(t % RING) * (MGRP * HDIM) + mt * 16 * HDIM
          : ring2 + (size_t)((t + 1) & 1) * (MGRP * HDIM) + mt * 16 * HDIM;
      // batched A-fragment loads (32 independent 8B LLC loads -> pipeline)
      half8 a[16];
#pragma unroll
      for (int ksl = 0; ksl < 16; ++ksl)
        a[ksl] = ring_ld16(abase + nlane * HDIM + ksl * 32 + quad * 8);

      floatx4 acc[4];
#pragma unroll
      for (int gg = 0; gg < 4; ++gg)
        acc[gg] = (kh == 0)
            ? (floatx4){bias_r[gg], bias_r[gg], bias_r[gg], bias_r[gg]}
            : (floatx4){0.f, 0.f, 0.f, 0.f};
      // 64 register-fed MFMAs: no memory ops in this loop
#pragma unroll
      for (int ksl = 0; ksl < 16; ++ksl) {
#pragma unroll
        for (int gg = 0; gg < 4; ++gg)
          acc[gg] = __builtin_amdgcn_mfma_f32_16x16x32_f16(a[ksl], breg[gg * 16 + ksl],
                                                           acc[gg], 0, 0, 0);
      }
      if (kh == 1) {
#pragma unroll
        for (int gg = 0; gg < 4; ++gg) pbase[(mt * 4 + gg) * 64 + lane] = acc[gg];
      }
      __syncthreads();
      float red[4];
      if (kh == 0) {
#pragma unroll
        for (int gg = 0; gg < 4; ++gg) acc[gg] += pbase[(mt * 4 + gg) * 64 + lane];
#pragma unroll
        for (int r = 0; r < 4; ++r) {
          float iv = acc[0][r], fv = acc[1][r], gv = acc[2][r], ov = acc[3][r];
          float cn = sigf(fv) * cstate[r] + sigf(iv) * tanhf(gv);
          float hn = sigf(ov) * tanhf(cn);
          cstate[r] = cn;
          tile2[(mt * 16 + quad * 4 + r) * 16 + nlane] = (_Float16)hn;
          red[r] = wl * hn;
        }
      }
      __syncthreads();
      // ring2 store (tid<128 cover the 32x16 tile) + verified release
      unsigned long long v = 0;
      _Float16* dst = nullptr;
      if (tid < 128) {
        v = *(const unsigned long long*)(tile2 + (tid >> 2) * 16 + (tid & 3) * 4);
        dst = ring2 + (size_t)(t & 1) * (MGRP * HDIM) + (tid >> 2) * HDIM +
              j * 16 + (tid & 3) * 4;
        ring_st8(dst, v);
      }
      __syncthreads();                 // stores issued & ack'd
      if (tid < 128) verify8(dst, v);  // proven readable at LLC
      __syncthreads();                 // all verified
      if (tid == 0) flag_st(myflag, (unsigned)(t + 1));  // release: ONE store
      // linear head: fire-and-forget, off the critical path
      if (kh == 0) {
#pragma unroll
        for (int r = 0; r < 4; ++r) {
          float v2 = red[r];
          v2 += __shfl_xor(v2, 1, 64);
          v2 += __shfl_xor(v2, 2, 64);
          v2 += __shfl_xor(v2, 4, 64);
          v2 += __shfl_xor(v2, 8, 64);
          red[r] = v2;
        }
        if (nlane == 0) {
#pragma unroll
          for (int r = 0; r < 4; ++r) {
            int b = g * MGRP + mt * 16 + quad * 4 + r;
            atomicAdd(out + (size_t)b * TSTEPS + t, red[r]);
          }
        }
      }
    }
  }
}

// ---------------------------------------------------------------------------
extern "C" void kernel_launch(void* const* d_in, const int* in_sizes, int n_in,
                              void* d_out, int out_size, void* d_ws, size_t ws_size,
                              hipStream_t stream) {
  const float* x    = (const float*)d_in[0];
  const float* Wih1 = (const float*)d_in[1];
  const float* Whh1 = (const float*)d_in[2];
  const float* bih1 = (const float*)d_in[3];
  const float* bhh1 = (const float*)d_in[4];
  const float* Wih2 = (const float*)d_in[5];
  const float* Whh2 = (const float*)d_in[6];
  const float* bih2 = (const float*)d_in[7];
  const float* bhh2 = (const float*)d_in[8];
  const float* Wlin = (const float*)d_in[9];
  const float* blin = (const float*)d_in[10];
  float* out = (float*)d_out;
  char* ws = (char*)d_ws;

  init_kernel<<<640, 256, 0, stream>>>(ws, out, blin);
  pack_kernel<<<1536, 256, 0, stream>>>(Whh1, Wih2, Whh2, ws);
  lstm_persist<<<256, 256, 0, stream>>>(x, Wih1, bih1, bhh1, bih2, bhh2, Wlin, out, ws);
}

// Round 10
// 2323.272 us; speedup vs baseline: 1.5711x; 1.5711x over previous
//
#include <hip/hip_runtime.h>
#include <hip/hip_fp16.h>

// ---------------------------------------------------------------------------
// 2-layer LSTM (T=512, B=128, H=512) + linear head, persistent-kernel design.
// Round 10: R7 compute core + contention-free flag fabric.
//  - Flags replicated per (consumer, producer): producer releases with 48
//    parallel NON-RETURNING atomicAdds to 48 private lines (RMW release =
//    the only flavor that never corrupted: R2/3/6/7; no verify needed).
//    Each consumer block polls ONLY its own line -> zero same-line RMW
//    serialization, zero poller storms.
//  - A-fragments: 16 x 16B global_load_dwordx4 sc0 sc1 in one asm block with
//    a SINGLE s_waitcnt -> half the LLC requests, no per-pair waits.
//  - Compute: register-resident B-slices (64 rows/wave), off-path head.
//  - 2 barriers/step (R7 had 3).
// ---------------------------------------------------------------------------

#define HDIM   512
#define TSTEPS 512
#define BATCH  128
#define DIN    5
#define NGRP   4
#define MGRP   32
#define NB1    16
#define NB2    32
#define RING   16

#define OFF_W1 0u            // packed layer1 weights: 16 blocks * 128KB = 2MB
#define OFF_W2 2097152u      // packed layer2 weights: 32 blocks * 128KB = 4MB
#define OFF_H1 6291456u      // h1 ring: 4 * 16 * 32 * 512 fp16 = 2MB
#define OFF_H2 8388608u      // h2 ring: 4 * 2 * 32 * 512 fp16 = 256KB
#define OFF_F1 8650752u      // flags1: 4 grp * 48 consumers * 128B = 24KB
#define OFF_F2 8675328u      // flags2: 4 grp * 48 consumers * 128B = 24KB
#define WS_END 8699904u
// flags1 consumer c: 0..15 = L1 block j ; 16..47 = L2 block j (kh0)
// flags2 consumer c: 0..31 = L2 block j (kh1) ; 32..47 = L1 block j (backpr.)
// Each consumer line: 32 u32 (128B); word p = producer p's cumulative count.

typedef _Float16 half8 __attribute__((ext_vector_type(8)));
typedef float    floatx4 __attribute__((ext_vector_type(4)));
typedef unsigned long long u64;

__device__ __forceinline__ float sigf(float v) { return 1.0f / (1.0f + __expf(-v)); }

__device__ __forceinline__ half8 as_h8(uint4 u) {
  union { uint4 u; half8 h; } c; c.u = u; return c.h;
}
__device__ __forceinline__ void ring_st8(_Float16* p, u64 v) {
  __hip_atomic_store((u64*)p, v, __ATOMIC_RELAXED, __HIP_MEMORY_SCOPE_AGENT);
}
// 16 pipelined 16B agent-coherent loads (sc0 sc1), ONE waitcnt.
__device__ __forceinline__ void lda16(const _Float16* p, uint4* a) {
  asm volatile(
      "global_load_dwordx4 %0, %16, off sc0 sc1\n\t"
      "global_load_dwordx4 %1, %16, off offset:64 sc0 sc1\n\t"
      "global_load_dwordx4 %2, %16, off offset:128 sc0 sc1\n\t"
      "global_load_dwordx4 %3, %16, off offset:192 sc0 sc1\n\t"
      "global_load_dwordx4 %4, %16, off offset:256 sc0 sc1\n\t"
      "global_load_dwordx4 %5, %16, off offset:320 sc0 sc1\n\t"
      "global_load_dwordx4 %6, %16, off offset:384 sc0 sc1\n\t"
      "global_load_dwordx4 %7, %16, off offset:448 sc0 sc1\n\t"
      "global_load_dwordx4 %8, %16, off offset:512 sc0 sc1\n\t"
      "global_load_dwordx4 %9, %16, off offset:576 sc0 sc1\n\t"
      "global_load_dwordx4 %10, %16, off offset:640 sc0 sc1\n\t"
      "global_load_dwordx4 %11, %16, off offset:704 sc0 sc1\n\t"
      "global_load_dwordx4 %12, %16, off offset:768 sc0 sc1\n\t"
      "global_load_dwordx4 %13, %16, off offset:832 sc0 sc1\n\t"
      "global_load_dwordx4 %14, %16, off offset:896 sc0 sc1\n\t"
      "global_load_dwordx4 %15, %16, off offset:960 sc0 sc1\n\t"
      "s_waitcnt vmcnt(0)"
      : "=v"(a[0]), "=v"(a[1]), "=v"(a[2]), "=v"(a[3]),
        "=v"(a[4]), "=v"(a[5]), "=v"(a[6]), "=v"(a[7]),
        "=v"(a[8]), "=v"(a[9]), "=v"(a[10]), "=v"(a[11]),
        "=v"(a[12]), "=v"(a[13]), "=v"(a[14]), "=v"(a[15])
      : "v"(p)
      : "memory");
}
// Poll ONE private consumer line: lane i (<n) reads word i; exit when all>=tgt.
__device__ __forceinline__ void poll_line(const unsigned* line, int n, unsigned tgt,
                                          int lane) {
  for (;;) {
    unsigned v = tgt;
    if (lane < n)
      v = __hip_atomic_load(line + lane, __ATOMIC_RELAXED, __HIP_MEMORY_SCOPE_AGENT);
    if (__all((int)(v >= tgt))) break;
  }
  __asm__ __volatile__("" ::: "memory");
}

// ---------------------------------------------------------------------------
extern "C" __global__ void init_kernel(char* __restrict__ ws, float* __restrict__ out,
                                       const float* __restrict__ blin) {
  unsigned tid = blockIdx.x * 256u + threadIdx.x;
  unsigned nz = (WS_END - OFF_H1) / 16u;  // 150528
  if (tid < nz) ((uint4*)(ws + OFF_H1))[tid] = make_uint4(0, 0, 0, 0);
  if (tid < (unsigned)(BATCH * TSTEPS)) out[tid] = blin[0];
}

// Pack fp32 weights -> fp16 MFMA B-fragment layout (unchanged since round 2).
extern "C" __global__ void pack_kernel(const float* __restrict__ Whh1,
                                       const float* __restrict__ Wih2,
                                       const float* __restrict__ Whh2,
                                       char* __restrict__ ws) {
  unsigned tid = blockIdx.x * 256u + threadIdx.x;
  const float* src;
  char* dst;
  if (tid < 131072u) {
    unsigned lane = tid & 63u, ks = (tid >> 6) & 15u, gg = (tid >> 10) & 3u,
             h = (tid >> 12) & 1u, j = tid >> 13;
    unsigned cg = j * 32u + h * 16u + (lane & 15u);
    unsigned row = gg * 512u + cg;
    unsigned k0 = ks * 32u + (lane >> 4) * 8u;
    src = Whh1 + (size_t)row * 512u + k0;
    dst = ws + OFF_W1 + (size_t)tid * 16u;
  } else {
    unsigned t2 = tid - 131072u;
    if (t2 >= 262144u) return;
    unsigned lane = t2 & 63u, ksl = (t2 >> 6) & 15u, gg = (t2 >> 10) & 3u,
             kh = (t2 >> 12) & 1u, j = t2 >> 13;
    unsigned cg = j * 16u + (lane & 15u);
    unsigned row = gg * 512u + cg;
    unsigned kp = kh * 512u + ksl * 32u + (lane >> 4) * 8u;
    src = (kp < 512u) ? (Wih2 + (size_t)row * 512u + kp)
                      : (Whh2 + (size_t)row * 512u + (kp - 512u));
    dst = ws + OFF_W2 + (size_t)t2 * 16u;
  }
  float4 lo = ((const float4*)src)[0];
  float4 hi = ((const float4*)src)[1];
  _Float16 v[8] = {(_Float16)lo.x, (_Float16)lo.y, (_Float16)lo.z, (_Float16)lo.w,
                   (_Float16)hi.x, (_Float16)hi.y, (_Float16)hi.z, (_Float16)hi.w};
  *(uint4*)dst = *(const uint4*)v;
}

// ---------------------------------------------------------------------------
extern "C" __global__ __launch_bounds__(256, 1) void lstm_persist(
    const float* __restrict__ x,
    const float* __restrict__ Wih1,
    const float* __restrict__ bih1, const float* __restrict__ bhh1,
    const float* __restrict__ bih2, const float* __restrict__ bhh2,
    const float* __restrict__ Wlin,
    float* __restrict__ out,
    char* __restrict__ ws) {
  __shared__ char smem[16384];

  const int blk = blockIdx.x;
  const int xcd = blk & 7;
  const int slot = blk >> 3;
  const int tid = threadIdx.x;
  const int wave = tid >> 6;
  const int lane = tid & 63;
  const int nlane = lane & 15;
  const int quad = lane >> 4;

  _Float16* h1ring = (_Float16*)(ws + OFF_H1);
  _Float16* h2ring = (_Float16*)(ws + OFF_H2);

  if (xcd >= NGRP) {
    // ------------------------------ layer 1 -------------------------------
    const int g = xcd - NGRP;
    const int j = slot;
    if (j >= NB1) return;
    const char* gW = ws + OFF_W1 + (size_t)j * 131072u;

    unsigned* f1g = (unsigned*)(ws + OFF_F1) + (size_t)g * 48 * 32;
    unsigned* f2g = (unsigned*)(ws + OFF_F2) + (size_t)g * 48 * 32;
    const unsigned* myline1 = f1g + (size_t)j * 32;         // 16 L1 producers
    const unsigned* mybp    = f2g + (size_t)(32 + j) * 32;  // 32 L2 producers
    _Float16* ring = h1ring + (size_t)g * (RING * MGRP * HDIM);
    _Float16* tile = (_Float16*)smem;  // 32x32 fp16 = 2KB

    const int mt = wave >> 1;  // batch half (16 rows)
    const int hh = wave & 1;   // column half (16 cols)
    const int cg = j * 32 + hh * 16 + nlane;

    // persistent B-slice: 64 rows x 16B/lane = 256 VGPRs, loaded once
    half8 breg[64];
#pragma unroll
    for (int r = 0; r < 64; ++r)
      breg[r] = *(const half8*)(gW + (size_t)((hh * 64 + r) * 64 + lane) * 16);

    float bias_r[4], wih[4][5];
    for (int gg = 0; gg < 4; ++gg) {
      int row = gg * 512 + cg;
      bias_r[gg] = bih1[row] + bhh1[row];
      for (int k = 0; k < 5; ++k) wih[gg][k] = Wih1[row * 5 + k];
    }
    float cstate[4] = {};

    for (int t = 0; t < TSTEPS; ++t) {
      // acquire: peers' h1(t-1) (own private line; all waves poll it)
      if (t) poll_line(myline1, NB1, (unsigned)t, lane);
      // amortized ring back-pressure (overwrite slot t%16 = h1(t-16)):
      // L2 flag >= t-8 means it consumed h1 up to step t-9 >= t-16.
      if ((t & 7) == 0 && t >= 16) poll_line(mybp, NB2, (unsigned)(t - 8), lane);

      // batched A-fragment loads: 16 x 16B, one waitcnt
      const _Float16* ap =
          ring + (size_t)((t + RING - 1) & (RING - 1)) * (MGRP * HDIM) +
          mt * 16 * HDIM + nlane * HDIM + quad * 8;
      uint4 areg[16];
      lda16(ap, areg);

      // acc init = bias + x_t @ W_ih1^T (fp32, K=5)
      float xr[4][5];
#pragma unroll
      for (int r = 0; r < 4; ++r) {
        int b = g * MGRP + mt * 16 + quad * 4 + r;
        const float* xp = x + ((size_t)t * BATCH + b) * DIN;
#pragma unroll
        for (int k = 0; k < 5; ++k) xr[r][k] = xp[k];
      }
      floatx4 acc[4];
#pragma unroll
      for (int gg = 0; gg < 4; ++gg) {
#pragma unroll
        for (int r = 0; r < 4; ++r) {
          float s = bias_r[gg];
#pragma unroll
          for (int k = 0; k < 5; ++k) s += xr[r][k] * wih[gg][k];
          acc[gg][r] = s;
        }
      }
      // 64 register-fed MFMAs
#pragma unroll
      for (int ks = 0; ks < 16; ++ks) {
        half8 av = as_h8(areg[ks]);
#pragma unroll
        for (int gg = 0; gg < 4; ++gg)
          acc[gg] = __builtin_amdgcn_mfma_f32_16x16x32_f16(av, breg[gg * 16 + ks],
                                                           acc[gg], 0, 0, 0);
      }
      // gates -> LDS transpose tile (32 rows x 32 cols fp16)
#pragma unroll
      for (int r = 0; r < 4; ++r) {
        float iv = acc[0][r], fv = acc[1][r], gv = acc[2][r], ov = acc[3][r];
        float cn = sigf(fv) * cstate[r] + sigf(iv) * tanhf(gv);
        float hn = sigf(ov) * tanhf(cn);
        cstate[r] = cn;
        tile[(mt * 16 + quad * 4 + r) * 32 + hh * 16 + nlane] = (_Float16)hn;
      }
      __syncthreads();
      // ring store: 256 threads x 8B, coalesced, agent-coherent
      {
        _Float16* hout = ring + (size_t)(t & (RING - 1)) * (MGRP * HDIM);
        u64 v = *(const u64*)(tile + (tid >> 3) * 32 + (tid & 7) * 4);
        ring_st8(hout + (tid >> 3) * HDIM + j * 32 + (tid & 7) * 4, v);
      }
      __syncthreads();  // drains vmcnt: all stores globally visible (R7-proven)
      // release: 48 parallel non-returning RMWs to private replicas
      if (tid < 48)
        __hip_atomic_fetch_add(f1g + (size_t)tid * 32 + j, 1u, __ATOMIC_RELAXED,
                               __HIP_MEMORY_SCOPE_AGENT);
      // no trailing barrier: next step's poll is the gate; tile reuse is
      // protected by the pre-store barrier of the NEXT step... (store phase
      // reads tile after the first barrier; next write happens after poll +
      // compute, and the drain barrier above orders all threads past reads)
    }
  } else {
    // ------------------------------ layer 2 -------------------------------
    const int g = xcd;
    const int j = slot;
    const char* gW = ws + OFF_W2 + (size_t)j * 131072u;

    unsigned* f1g = (unsigned*)(ws + OFF_F1) + (size_t)g * 48 * 32;
    unsigned* f2g = (unsigned*)(ws + OFF_F2) + (size_t)g * 48 * 32;
    const unsigned* myline1 = f1g + (size_t)(16 + j) * 32;  // 16 L1 producers
    const unsigned* myline2 = f2g + (size_t)j * 32;         // 32 L2 producers
    const _Float16* h1rd = h1ring + (size_t)g * (RING * MGRP * HDIM);
    _Float16* ring2 = h2ring + (size_t)g * (2 * MGRP * HDIM);
    floatx4* pbase = (floatx4*)smem;                 // 8KB
    _Float16* tile2 = (_Float16*)(smem + 8192);      // 32x16 fp16 = 1KB

    const int kh = wave & 1;   // 0 -> W_ih2 . h1(t), 1 -> W_hh2 . h2(t-1)
    const int mt = wave >> 1;  // batch half
    const int cg = j * 16 + nlane;

    // persistent B-slice: 64 rows x 16B/lane = 256 VGPRs, loaded once
    half8 breg[64];
#pragma unroll
    for (int r = 0; r < 64; ++r)
      breg[r] = *(const half8*)(gW + (size_t)((kh * 64 + r) * 64 + lane) * 16);

    float bias_r[4];
    for (int gg = 0; gg < 4; ++gg) {
      int row = gg * 512 + cg;
      bias_r[gg] = bih2[row] + bhh2[row];
    }
    const float wl = Wlin[cg];
    float cstate[4] = {};

    for (int t = 0; t < TSTEPS; ++t) {
      // acquire: kh0 needs h1(t) (>= t+1); kh1 needs peers' h2(t-1) (>= t)
      if (kh == 0) poll_line(myline1, NB1, (unsigned)(t + 1), lane);
      else if (t)  poll_line(myline2, NB2, (unsigned)t, lane);

      const _Float16* abase = (kh == 0)
          ? h1rd + (size_t)(t & (RING - 1)) * (MGRP * HDIM) + mt * 16 * HDIM +
                nlane * HDIM + quad * 8
          : ring2 + (size_t)((t + 1) & 1) * (MGRP * HDIM) + mt * 16 * HDIM +
                nlane * HDIM + quad * 8;
      uint4 areg[16];
      lda16(abase, areg);

      floatx4 acc[4];
#pragma unroll
      for (int gg = 0; gg < 4; ++gg)
        acc[gg] = (kh == 0)
            ? (floatx4){bias_r[gg], bias_r[gg], bias_r[gg], bias_r[gg]}
            : (floatx4){0.f, 0.f, 0.f, 0.f};
#pragma unroll
      for (int ks = 0; ks < 16; ++ks) {
        half8 av = as_h8(areg[ks]);
#pragma unroll
        for (int gg = 0; gg < 4; ++gg)
          acc[gg] = __builtin_amdgcn_mfma_f32_16x16x32_f16(av, breg[gg * 16 + ks],
                                                           acc[gg], 0, 0, 0);
      }
      if (kh == 1) {
#pragma unroll
        for (int gg = 0; gg < 4; ++gg) pbase[(mt * 4 + gg) * 64 + lane] = acc[gg];
      }
      __syncthreads();
      float red[4];
      if (kh == 0) {
#pragma unroll
        for (int gg = 0; gg < 4; ++gg) acc[gg] += pbase[(mt * 4 + gg) * 64 + lane];
#pragma unroll
        for (int r = 0; r < 4; ++r) {
          float iv = acc[0][r], fv = acc[1][r], gv = acc[2][r], ov = acc[3][r];
          float cn = sigf(fv) * cstate[r] + sigf(iv) * tanhf(gv);
          float hn = sigf(ov) * tanhf(cn);
          cstate[r] = cn;
          tile2[(mt * 16 + quad * 4 + r) * 16 + nlane] = (_Float16)hn;
          red[r] = wl * hn;
        }
      }
      __syncthreads();
      // ring2 store: 128 threads x 8B
      if (tid < 128) {
        u64 v = *(const u64*)(tile2 + (tid >> 2) * 16 + (tid & 3) * 4);
        ring_st8(ring2 + (size_t)(t & 1) * (MGRP * HDIM) + (tid >> 2) * HDIM +
                     j * 16 + (tid & 3) * 4, v);
      }
      __syncthreads();  // drains vmcnt before release
      // release: 48 parallel non-returning RMWs to private replicas
      if (tid < 48)
        __hip_atomic_fetch_add(f2g + (size_t)tid * 32 + j, 1u, __ATOMIC_RELAXED,
                               __HIP_MEMORY_SCOPE_AGENT);
      // linear head: fire-and-forget, off the critical path
      if (kh == 0) {
#pragma unroll
        for (int r = 0; r < 4; ++r) {
          float v2 = red[r];
          v2 += __shfl_xor(v2, 1, 64);
          v2 += __shfl_xor(v2, 2, 64);
          v2 += __shfl_xor(v2, 4, 64);
          v2 += __shfl_xor(v2, 8, 64);
          red[r] = v2;
        }
        if (nlane == 0) {
#pragma unroll
          for (int r = 0; r < 4; ++r) {
            int b = g * MGRP + mt * 16 + quad * 4 + r;
            atomicAdd(out + (size_t)b * TSTEPS + t, red[r]);
          }
        }
      }
    }
  }
}

// ---------------------------------------------------------------------------
extern "C" void kernel_launch(void* const* d_in, const int* in_sizes, int n_in,
                              void* d_out, int out_size, void* d_ws, size_t ws_size,
                              hipStream_t stream) {
  const float* x    = (const float*)d_in[0];
  const float* Wih1 = (const float*)d_in[1];
  const float* Whh1 = (const float*)d_in[2];
  const float* bih1 = (const float*)d_in[3];
  const float* bhh1 = (const float*)d_in[4];
  const float* Wih2 = (const float*)d_in[5];
  const float* Whh2 = (const float*)d_in[6];
  const float* bih2 = (const float*)d_in[7];
  const float* bhh2 = (const float*)d_in[8];
  const float* Wlin = (const float*)d_in[9];
  const float* blin = (const float*)d_in[10];
  float* out = (float*)d_out;
  char* ws = (char*)d_ws;

  init_kernel<<<640, 256, 0, stream>>>(ws, out, blin);
  pack_kernel<<<1536, 256, 0, stream>>>(Whh1, Wih2, Whh2, ws);
  lstm_persist<<<256, 256, 0, stream>>>(x, Wih1, bih1, bhh1, bih2, bhh2, Wlin, out, ws);
}